// Round 7
// baseline (3032.725 us; speedup 1.0000x reference)
//
#include <hip/hip_runtime.h>

typedef unsigned long long u64;
typedef unsigned int u32;

#define KNN 19             // neighbors used (reference k=20 incl. self, minus self)
#define TAU_K 20           // 20th smallest incl. self == 19th excl. self
#define GRES 32            // grid cells per axis
#define NCELLS (GRES * GRES * GRES)
#define MAXBLK 256         // candidate blocks (F/64); F=16384 -> 256
#define NSLOT 64           // collector blocks per group
#define LCAP 16            // per-lane LDS hit slots in k_collect
#define WIN 320            // tau window size (Morton-sorted candidates)
#define INIT_KEY (~0ULL)

// ---------------------------------------------------------------------------
// Kernel 1: centroids + edges + Morton cell key + cell histogram.
// Centroid/edge math replicates reference op order exactly (contract off).
// Quantization affects binning quality only, never correctness.
// ---------------------------------------------------------------------------
__device__ __forceinline__ u32 expand5(u32 x) {
  u32 m = 0;
  m |= (x & 1u);
  m |= (x & 2u) << 2;
  m |= (x & 4u) << 4;
  m |= (x & 8u) << 6;
  m |= (x & 16u) << 8;
  return m;
}

__global__ __launch_bounds__(256) void k_prep(
    const float* __restrict__ verts, const int* __restrict__ faces,
    float4* __restrict__ cent, float4* __restrict__ edges,
    u32* __restrict__ cellkey, u32* __restrict__ hist, int F) {
  #pragma clang fp contract(off)
  int f = blockIdx.x * 256 + threadIdx.x;
  if (f >= F) return;
  int i0 = faces[f * 3 + 0];
  int i1 = faces[f * 3 + 1];
  int i2 = faces[f * 3 + 2];
  float v0x = verts[i0 * 3 + 0], v0y = verts[i0 * 3 + 1], v0z = verts[i0 * 3 + 2];
  float v1x = verts[i1 * 3 + 0], v1y = verts[i1 * 3 + 1], v1z = verts[i1 * 3 + 2];
  float v2x = verts[i2 * 3 + 0], v2y = verts[i2 * 3 + 1], v2z = verts[i2 * 3 + 2];

  float cx = ((v0x + v1x) + v2x) / 3.0f;
  float cy = ((v0y + v1y) + v2y) / 3.0f;
  float cz = ((v0z + v1z) + v2z) / 3.0f;
  cent[f] = make_float4(cx, cy, cz, 0.0f);

  edges[f * 3 + 0] = make_float4(v1x - v0x, v1y - v0y, v1z - v0z, 0.0f);
  edges[f * 3 + 1] = make_float4(v2x - v1x, v2y - v1y, v2z - v1z, 0.0f);
  edges[f * 3 + 2] = make_float4(v0x - v2x, v0y - v2y, v0z - v2z, 0.0f);

  int qx = (int)((cx + 6.0f) * (GRES / 12.0f));
  int qy = (int)((cy + 6.0f) * (GRES / 12.0f));
  int qz = (int)((cz + 6.0f) * (GRES / 12.0f));
  qx = qx < 0 ? 0 : (qx > GRES - 1 ? GRES - 1 : qx);
  qy = qy < 0 ? 0 : (qy > GRES - 1 ? GRES - 1 : qy);
  qz = qz < 0 ? 0 : (qz > GRES - 1 ? GRES - 1 : qz);
  u32 m = expand5((u32)qx) | (expand5((u32)qy) << 1) | (expand5((u32)qz) << 2);
  cellkey[f] = m;
  atomicAdd(&hist[m], 1u);
}

// ---------------------------------------------------------------------------
// Kernel 2: exclusive scan of the 32768-cell histogram (one block).
// ---------------------------------------------------------------------------
__global__ __launch_bounds__(1024) void k_scan(
    const u32* __restrict__ hist, u32* __restrict__ cursor) {
  __shared__ u32 sums[1024];
  int t = threadIdx.x;
  int base = t * (NCELLS / 1024);
  u32 s = 0;
  for (int i = 0; i < NCELLS / 1024; ++i) s += hist[base + i];
  sums[t] = s;
  __syncthreads();
  for (int o = 1; o < 1024; o <<= 1) {
    u32 v = (t >= o) ? sums[t - o] : 0u;
    __syncthreads();
    sums[t] += v;
    __syncthreads();
  }
  u32 run = sums[t] - s;
  for (int i = 0; i < NCELLS / 1024; ++i) {
    cursor[base + i] = run;
    run += hist[base + i];
  }
}

// ---------------------------------------------------------------------------
// Kernel 3: scatter into Morton-sorted order (racy intra-cell order; final
// output depends only on exact key-ranked sets -> deterministic).
// ---------------------------------------------------------------------------
__global__ __launch_bounds__(256) void k_scatter(
    const float4* __restrict__ cent, const u32* __restrict__ cellkey,
    u32* __restrict__ cursor, u32* __restrict__ ids,
    float4* __restrict__ centS, int F) {
  int f = blockIdx.x * 256 + threadIdx.x;
  if (f >= F) return;
  u32 pos = atomicAdd(&cursor[cellkey[f]], 1u);
  ids[pos] = (u32)f;
  centS[pos] = cent[f];
}

// ---------------------------------------------------------------------------
// Kernel 4: per-64-point-block bounding boxes.
// ---------------------------------------------------------------------------
__global__ __launch_bounds__(64) void k_bbox(
    const float4* __restrict__ centS, float4* __restrict__ blo,
    float4* __restrict__ bhi, int F) {
  int b = blockIdx.x;
  int t = threadIdx.x;
  int idx = b * 64 + t;
  bool ok = idx < F;
  float4 v = centS[ok ? idx : 0];
  float lx = ok ? v.x : __builtin_inff(), hx = ok ? v.x : -__builtin_inff();
  float ly = ok ? v.y : __builtin_inff(), hy = ok ? v.y : -__builtin_inff();
  float lz = ok ? v.z : __builtin_inff(), hz = ok ? v.z : -__builtin_inff();
  for (int m = 1; m < 64; m <<= 1) {
    lx = fminf(lx, __shfl_xor(lx, m));
    ly = fminf(ly, __shfl_xor(ly, m));
    lz = fminf(lz, __shfl_xor(lz, m));
    hx = fmaxf(hx, __shfl_xor(hx, m));
    hy = fmaxf(hy, __shfl_xor(hy, m));
    hz = fmaxf(hz, __shfl_xor(hz, m));
  }
  if (t == 0) {
    blo[b] = make_float4(lx, ly, lz, 0.0f);
    bhi[b] = make_float4(hx, hy, hz, 0.0f);
  }
}

// ---------------------------------------------------------------------------
// Kernel 5: tau'[pos] = 20th smallest (incl. self) d2 over a 320-wide Morton
// window, * (1+2e-6) fma-noise margin. Valid upper bound of the true 19th-
// excl-self distance (subset order stat >= full-set order stat). 4 waves per
// 64-face group, 80 window candidates each, branchless float net-20; merged
// via LDS by wave 0. Also writes group-max tau and zeroes collect counters.
// ---------------------------------------------------------------------------
__global__ __launch_bounds__(256) void k_tau(
    const float4* __restrict__ centS, float* __restrict__ tauS,
    float* __restrict__ gtau, u32* __restrict__ cntS, int F) {
  __shared__ float s_m[3 * TAU_K * 64];   // 15 KB

  int lane = threadIdx.x & 63;
  int w    = threadIdx.x >> 6;
  int g    = blockIdx.x;
  int myPos = g * 64 + lane;
  bool live = myPos < F;
  float4 me = centS[live ? myPos : 0];

  float L[TAU_K];
  #pragma unroll
  for (int p = 0; p < TAU_K; ++p) L[p] = __builtin_inff();

  int ws0 = g * 64 - 128 + w * (WIN / 4);
  #pragma unroll 2
  for (int t = 0; t < WIN / 4; ++t) {
    int jj = ws0 + t;
    if ((unsigned)jj < (unsigned)F) {     // wave-uniform branch
      float4 cj = centS[jj];
      float dx = me.x - cj.x;
      float dy = me.y - cj.y;
      float dz = me.z - cj.z;
      float d2 = fmaf(dz, dz, fmaf(dy, dy, dx * dx));
      float prev = d2;
      #pragma unroll
      for (int p = 0; p < TAU_K; ++p) {
        float o = L[p];
        L[p] = fminf(o, prev);
        prev = fmaxf(o, d2);
      }
    }
  }

  if (w > 0) {
    #pragma unroll
    for (int p = 0; p < TAU_K; ++p)
      s_m[((w - 1) * TAU_K + p) * 64 + lane] = L[p];
  }
  __syncthreads();

  if (w == 0) {
    for (int wm = 0; wm < 3; ++wm) {
      #pragma unroll
      for (int p = 0; p < TAU_K; ++p) {
        float x = s_m[(wm * TAU_K + p) * 64 + lane];
        float prev = x;
        #pragma unroll
        for (int q = 0; q < TAU_K; ++q) {
          float o = L[q];
          L[q] = fminf(o, prev);
          prev = fmaxf(o, x);
        }
      }
    }
    float t = L[TAU_K - 1] * (1.0f + 2e-6f);
    if (live) { tauS[myPos] = t; cntS[myPos] = 0u; }
    float gm = live ? t : 0.0f;
    #pragma unroll
    for (int m = 1; m < 64; m <<= 1) gm = fmaxf(gm, __shfl_xor(gm, m));
    if (lane == 0) gtau[g] = gm;
  }
}

// ---------------------------------------------------------------------------
// Kernel 6: per-group candidate-block list: blocks whose bbox min-d2 to the
// group's bbox (conservative margin) can beat the group's max tau. Ballot-
// compacted, order-deterministic (ascending block index).
// ---------------------------------------------------------------------------
__global__ __launch_bounds__(64) void k_blist(
    const float4* __restrict__ blo, const float4* __restrict__ bhi,
    const float* __restrict__ gtau, u32* __restrict__ blist,
    u32* __restrict__ blen, int nblk) {
  int g = blockIdx.x;
  int lane = threadIdx.x;
  float4 gl = blo[g], gh = bhi[g];
  float gt = gtau[g];
  int base = 0;
  for (int b0 = 0; b0 < nblk; b0 += 64) {
    int b = b0 + lane;
    bool keep = false;
    if (b < nblk) {
      float4 lo = blo[b], hi = bhi[b];
      float dx = fmaxf(0.0f, fmaxf(lo.x - gh.x, gl.x - hi.x));
      float dy = fmaxf(0.0f, fmaxf(lo.y - gh.y, gl.y - hi.y));
      float dz = fmaxf(0.0f, fmaxf(lo.z - gh.z, gl.z - hi.z));
      float dmin = ((dx * dx + dy * dy) + dz * dz) * 0.999999f;
      keep = dmin <= gt;
    }
    u64 mask = __ballot(keep);
    int prefix = __popcll(mask & ((1ull << lane) - 1ull));
    if (keep) blist[g * MAXBLK + base + prefix] = (u32)b;
    base += __popcll(mask);
  }
  if (lane == 0) blen[g] = (u32)base;
}

// ---------------------------------------------------------------------------
// Kernel 7: collect. Grid = groups x NSLOT; block = 64 threads = 1 wave;
// slot s handles list entries s, s+NSLOT, ... Lane = one face of the group.
// Exact contract-off d2 <= tau'[face] -> superset of the true top-19.
// Hits buffered in LDS, flushed with one atomicAdd per ~8 hits (R4 pattern).
// ---------------------------------------------------------------------------
__global__ __launch_bounds__(64) void k_collect(
    const float4* __restrict__ centS, const float* __restrict__ tauS,
    const u32* __restrict__ blist, const u32* __restrict__ blen,
    u32* __restrict__ cntS, u64* __restrict__ bufS, int F, int cap) {
  #pragma clang fp contract(off)
  __shared__ u64 lbuf[64 * LCAP];   // 8 KB

  int bid  = blockIdx.x;
  int g    = bid >> 6;          // NSLOT = 64
  int slot = bid & (NSLOT - 1);
  int len  = (int)blen[g];
  if (slot >= len) return;

  int lane = threadIdx.x;
  int myPos = g * 64 + lane;
  bool live = myPos < F;
  float4 me = centS[live ? myPos : 0];
  float tf = live ? tauS[myPos] : -1.0f;
  int n = 0;

  for (int li = slot; li < len; li += NSLOT) {
    int cb = (int)blist[g * MAXBLK + li];
    int base = cb * 64;
    int cnt = (base + 64 <= F) ? 64 : (F - base);
    #pragma unroll 4
    for (int q = 0; q < cnt; ++q) {
      int jj = base + q;                       // wave-uniform
      float4 cj = centS[jj];
      float dx = me.x - cj.x;
      float dy = me.y - cj.y;
      float dz = me.z - cj.z;
      float d2 = (dx * dx + dy * dy) + dz * dz;   // bit-exact reference form
      if (d2 <= tf && jj != myPos) {
        u64 key = (((u64)__float_as_uint(d2)) << 32) | (u64)jj;  // jj: sorted pos
        if (n < LCAP) {
          lbuf[lane * LCAP + n] = key;
          ++n;
        } else {
          u32 pos = atomicAdd(&cntS[myPos], 1u);
          if (pos < (u32)cap) bufS[(size_t)myPos * cap + pos] = key;
        }
      }
    }
    if (n >= 8) {
      u32 basep = atomicAdd(&cntS[myPos], (u32)n);
      for (int i = 0; i < n; ++i) {
        u32 pp = basep + (u32)i;
        if (pp < (u32)cap) bufS[(size_t)myPos * cap + pp] = lbuf[lane * LCAP + i];
      }
      n = 0;
    }
  }
  if (n > 0) {
    u32 basep = atomicAdd(&cntS[myPos], (u32)n);
    for (int i = 0; i < n; ++i) {
      u32 pp = basep + (u32)i;
      if (pp < (u32)cap) bufS[(size_t)myPos * cap + pp] = lbuf[lane * LCAP + i];
    }
  }
}

// ---------------------------------------------------------------------------
// Kernel 8: exact top-19 per face over collected keys. Keys are rebuilt with
// ORIGINAL ids so ordering == lax.top_k's (stable lower-index tie-break).
// Unconditional-correctness fallback: full rescan if buffer unusable.
// ---------------------------------------------------------------------------
__global__ __launch_bounds__(256) void k_select(
    const float4* __restrict__ centS, const u32* __restrict__ ids,
    const u32* __restrict__ cntS, const u64* __restrict__ bufS,
    int* __restrict__ nearest, int F, int cap) {
  #pragma clang fp contract(off)
  int pos = blockIdx.x * 256 + threadIdx.x;
  if (pos >= F) return;

  u64 L[KNN];
  #pragma unroll
  for (int p = 0; p < KNN; ++p) L[p] = INIT_KEY;

  int n = (int)cntS[pos];
  if (n >= KNN && n <= cap) {
    const u64* row = bufS + (size_t)pos * cap;
    for (int i = 0; i < n; ++i) {
      u64 kraw = row[i];
      u32 jpos = (u32)kraw;                       // sorted position
      u64 key = (kraw & 0xFFFFFFFF00000000ull) | (u64)ids[jpos];  // orig id
      if (key < L[KNN - 1]) {
        u64 prev = key;
        #pragma unroll
        for (int p = 0; p < KNN; ++p) {
          u64 o = L[p];
          L[p] = prev < o ? prev : o;
          prev = key < o ? o : key;
        }
      }
    }
  } else {
    float4 me = centS[pos];
    for (int jj = 0; jj < F; ++jj) {
      if (jj == pos) continue;
      float4 cj = centS[jj];
      float dx = me.x - cj.x;
      float dy = me.y - cj.y;
      float dz = me.z - cj.z;
      float d2 = (dx * dx + dy * dy) + dz * dz;
      u64 key = (((u64)__float_as_uint(d2)) << 32) | (u64)ids[jj];
      if (key < L[KNN - 1]) {
        u64 prev = key;
        #pragma unroll
        for (int p = 0; p < KNN; ++p) {
          u64 o = L[p];
          L[p] = prev < o ? prev : o;
          prev = key < o ? o : key;
        }
      }
    }
  }

  u32 myId = ids[pos];
  #pragma unroll
  for (int p = 0; p < KNN; ++p)
    nearest[(size_t)myId * KNN + p] = (int)(u32)L[p];
}

// ---------------------------------------------------------------------------
// Kernel 9: one thread per (face, neighbor): 3x3 segment-pair crossing count.
// ---------------------------------------------------------------------------
__global__ __launch_bounds__(256) void k_cross(
    const float4* __restrict__ edges, const int* __restrict__ nearest,
    int* __restrict__ ccbuf, int total) {
  #pragma clang fp contract(off)
  int idx = blockIdx.x * 256 + threadIdx.x;
  if (idx >= total) return;
  int f = idx / KNN;
  int g = nearest[idx];

  float e[3][3], nb[3][3];
  #pragma unroll
  for (int a = 0; a < 3; ++a) {
    float4 t = edges[f * 3 + a];
    e[a][0] = t.x; e[a][1] = t.y; e[a][2] = t.z;
  }
  #pragma unroll
  for (int b = 0; b < 3; ++b) {
    float4 t = edges[g * 3 + b];
    nb[b][0] = t.x; nb[b][1] = t.y; nb[b][2] = t.z;
  }

  int cc = 0;
  #pragma unroll
  for (int a = 0; a < 3; ++a) {
    #pragma unroll
    for (int b = 0; b < 3; ++b) {
      float c0 = e[a][1] * nb[b][2] - e[a][2] * nb[b][1];
      float c1 = e[a][2] * nb[b][0] - e[a][0] * nb[b][2];
      float c2 = e[a][0] * nb[b][1] - e[a][1] * nb[b][0];
      float den = (c0 * e[a][0] + c1 * e[a][1]) + c2 * e[a][2];
      float tn  = (c0 * nb[b][0] + c1 * nb[b][1]) + c2 * nb[b][2];
      float un  = (c0 * e[b][0]  + c1 * e[b][1])  + c2 * e[b][2];
      float t = tn / den;
      float u = un / den;
      if (t >= 0.0f && t <= 1.0f && u >= 0.0f && u <= 1.0f) ++cc;
    }
  }
  ccbuf[idx] = cc;
}

// ---------------------------------------------------------------------------
// Kernel 10: per-face weighted sum, block-reduced.
// ---------------------------------------------------------------------------
__global__ __launch_bounds__(256) void k_wsum(
    const int* __restrict__ ccbuf, const float* __restrict__ probs,
    float* __restrict__ partial, int F) {
  int f = blockIdx.x * 256 + threadIdx.x;
  float w = 0.0f;
  if (f < F) {
    int c = 0;
    #pragma unroll
    for (int s = 0; s < KNN; ++s) c += ccbuf[(size_t)f * KNN + s];
    w = probs[f] * (float)c;
  }
  __shared__ float red[256];
  red[threadIdx.x] = w;
  __syncthreads();
  #pragma unroll
  for (int s = 128; s > 0; s >>= 1) {
    if (threadIdx.x < s) red[threadIdx.x] += red[threadIdx.x + s];
    __syncthreads();
  }
  if (threadIdx.x == 0) partial[blockIdx.x] = red[0];
}

// ---------------------------------------------------------------------------
// Kernel 11: deterministic final reduction; /F exact (F = 2^14)
// ---------------------------------------------------------------------------
__global__ void k_final(const float* __restrict__ partial, float* __restrict__ out,
                        int nblk, float invF) {
  if (threadIdx.x == 0 && blockIdx.x == 0) {
    float s = 0.0f;
    for (int i = 0; i < nblk; ++i) s += partial[i];
    out[0] = s * invF;
  }
}

extern "C" void kernel_launch(void* const* d_in, const int* in_sizes, int n_in,
                              void* d_out, int out_size, void* d_ws, size_t ws_size,
                              hipStream_t stream) {
  const float* verts = (const float*)d_in[0];
  const int*   faces = (const int*)d_in[1];
  const float* probs = (const float*)d_in[2];
  float* out = (float*)d_out;
  const int F = in_sizes[2];            // 16384
  const int total = F * KNN;
  const int nblk64 = (F + 63) / 64;     // 256 groups / candidate blocks

  char* ws = (char*)d_ws;
  size_t off = 0;
  auto take = [&](size_t bytes) { char* p = ws + off; off += (bytes + 255) & ~(size_t)255; return p; };

  float4* cent    = (float4*)take((size_t)F * sizeof(float4));
  float4* edges   = (float4*)take((size_t)F * 3 * sizeof(float4));
  u32*    cellkey = (u32*)   take((size_t)F * sizeof(u32));
  u32*    hist    = (u32*)   take((size_t)NCELLS * sizeof(u32));
  u32*    cursor  = (u32*)   take((size_t)NCELLS * sizeof(u32));
  u32*    ids     = (u32*)   take((size_t)F * sizeof(u32));
  float4* centS   = (float4*)take((size_t)F * sizeof(float4));
  float4* blo     = (float4*)take((size_t)nblk64 * sizeof(float4));
  float4* bhi     = (float4*)take((size_t)nblk64 * sizeof(float4));
  float*  tauS    = (float*) take((size_t)F * sizeof(float));
  float*  gtau    = (float*) take((size_t)nblk64 * sizeof(float));
  u32*    cntS    = (u32*)   take((size_t)F * sizeof(u32));
  u32*    blist   = (u32*)   take((size_t)nblk64 * MAXBLK * sizeof(u32));
  u32*    blen    = (u32*)   take((size_t)nblk64 * sizeof(u32));
  int*    nearest = (int*)   take((size_t)total * sizeof(int));
  int*    ccbuf   = (int*)   take((size_t)total * sizeof(int));
  float*  partial = (float*) take(256 * sizeof(float));

  size_t avail = (ws_size > off) ? (ws_size - off) : 0;
  size_t capz = avail / ((size_t)F * sizeof(u64));
  int cap = capz > 96 ? 96 : (int)capz;      // per-face collect capacity
  u64* bufS = (u64*)(ws + off);

  int nblk256 = (F + 255) / 256;        // 64

  hipMemsetAsync(hist, 0, (size_t)NCELLS * sizeof(u32), stream);
  k_prep   <<<nblk256, 256, 0, stream>>>(verts, faces, cent, edges, cellkey, hist, F);
  k_scan   <<<1, 1024, 0, stream>>>(hist, cursor);
  k_scatter<<<nblk256, 256, 0, stream>>>(cent, cellkey, cursor, ids, centS, F);
  k_bbox   <<<nblk64, 64, 0, stream>>>(centS, blo, bhi, F);
  k_tau    <<<nblk64, 256, 0, stream>>>(centS, tauS, gtau, cntS, F);
  k_blist  <<<nblk64, 64, 0, stream>>>(blo, bhi, gtau, blist, blen, nblk64);
  k_collect<<<nblk64 * NSLOT, 64, 0, stream>>>(centS, tauS, blist, blen, cntS, bufS, F, cap);
  k_select <<<nblk256, 256, 0, stream>>>(centS, ids, cntS, bufS, nearest, F, cap);
  k_cross  <<<(total + 255) / 256, 256, 0, stream>>>(edges, nearest, ccbuf, total);
  k_wsum   <<<nblk256, 256, 0, stream>>>(ccbuf, probs, partial, F);
  k_final  <<<1, 64, 0, stream>>>(partial, out, nblk256, 1.0f / (float)F);
}

// Round 8
// 412.593 us; speedup vs baseline: 7.3504x; 7.3504x over previous
//
#include <hip/hip_runtime.h>

typedef unsigned long long u64;
typedef unsigned int u32;

#define KNN 19             // neighbors used (reference k=20 incl. self, minus self)
#define TAU_K 20           // 20th smallest incl. self == 19th excl. self
#define GRES 32            // grid cells per axis
#define NCELLS (GRES * GRES * GRES)
#define MAXBLK 256         // candidate blocks (F/64); F=16384 -> 256
#define NSLOT 64           // collector blocks per group
#define LCAP 16            // per-lane LDS hit slots in k_collect
#define WIN 320            // tau window size (Morton-sorted candidates)
#define FIXBLKS 1024       // k_fix grid (fixed; strides over bad list)
#define INIT_KEY (~0ULL)

// ---------------------------------------------------------------------------
// Kernel 1: centroids + edges + Morton cell key + cell histogram.
// Centroid/edge math replicates reference op order exactly (contract off).
// ---------------------------------------------------------------------------
__device__ __forceinline__ u32 expand5(u32 x) {
  u32 m = 0;
  m |= (x & 1u);
  m |= (x & 2u) << 2;
  m |= (x & 4u) << 4;
  m |= (x & 8u) << 6;
  m |= (x & 16u) << 8;
  return m;
}

__global__ __launch_bounds__(256) void k_prep(
    const float* __restrict__ verts, const int* __restrict__ faces,
    float4* __restrict__ cent, float4* __restrict__ edges,
    u32* __restrict__ cellkey, u32* __restrict__ hist, int F) {
  #pragma clang fp contract(off)
  int f = blockIdx.x * 256 + threadIdx.x;
  if (f >= F) return;
  int i0 = faces[f * 3 + 0];
  int i1 = faces[f * 3 + 1];
  int i2 = faces[f * 3 + 2];
  float v0x = verts[i0 * 3 + 0], v0y = verts[i0 * 3 + 1], v0z = verts[i0 * 3 + 2];
  float v1x = verts[i1 * 3 + 0], v1y = verts[i1 * 3 + 1], v1z = verts[i1 * 3 + 2];
  float v2x = verts[i2 * 3 + 0], v2y = verts[i2 * 3 + 1], v2z = verts[i2 * 3 + 2];

  float cx = ((v0x + v1x) + v2x) / 3.0f;
  float cy = ((v0y + v1y) + v2y) / 3.0f;
  float cz = ((v0z + v1z) + v2z) / 3.0f;
  cent[f] = make_float4(cx, cy, cz, 0.0f);

  edges[f * 3 + 0] = make_float4(v1x - v0x, v1y - v0y, v1z - v0z, 0.0f);
  edges[f * 3 + 1] = make_float4(v2x - v1x, v2y - v1y, v2z - v1z, 0.0f);
  edges[f * 3 + 2] = make_float4(v0x - v2x, v0y - v2y, v0z - v2z, 0.0f);

  int qx = (int)((cx + 6.0f) * (GRES / 12.0f));
  int qy = (int)((cy + 6.0f) * (GRES / 12.0f));
  int qz = (int)((cz + 6.0f) * (GRES / 12.0f));
  qx = qx < 0 ? 0 : (qx > GRES - 1 ? GRES - 1 : qx);
  qy = qy < 0 ? 0 : (qy > GRES - 1 ? GRES - 1 : qy);
  qz = qz < 0 ? 0 : (qz > GRES - 1 ? GRES - 1 : qz);
  u32 m = expand5((u32)qx) | (expand5((u32)qy) << 1) | (expand5((u32)qz) << 2);
  cellkey[f] = m;
  atomicAdd(&hist[m], 1u);
}

// ---------------------------------------------------------------------------
// Kernel 2: exclusive scan of the 32768-cell histogram (one block).
// ---------------------------------------------------------------------------
__global__ __launch_bounds__(1024) void k_scan(
    const u32* __restrict__ hist, u32* __restrict__ cursor) {
  __shared__ u32 sums[1024];
  int t = threadIdx.x;
  int base = t * (NCELLS / 1024);
  u32 s = 0;
  for (int i = 0; i < NCELLS / 1024; ++i) s += hist[base + i];
  sums[t] = s;
  __syncthreads();
  for (int o = 1; o < 1024; o <<= 1) {
    u32 v = (t >= o) ? sums[t - o] : 0u;
    __syncthreads();
    sums[t] += v;
    __syncthreads();
  }
  u32 run = sums[t] - s;
  for (int i = 0; i < NCELLS / 1024; ++i) {
    cursor[base + i] = run;
    run += hist[base + i];
  }
}

// ---------------------------------------------------------------------------
// Kernel 3: scatter into Morton-sorted order (racy intra-cell order; final
// output depends only on exact key-ranked sets -> deterministic).
// ---------------------------------------------------------------------------
__global__ __launch_bounds__(256) void k_scatter(
    const float4* __restrict__ cent, const u32* __restrict__ cellkey,
    u32* __restrict__ cursor, u32* __restrict__ ids,
    float4* __restrict__ centS, int F) {
  int f = blockIdx.x * 256 + threadIdx.x;
  if (f >= F) return;
  u32 pos = atomicAdd(&cursor[cellkey[f]], 1u);
  ids[pos] = (u32)f;
  centS[pos] = cent[f];
}

// ---------------------------------------------------------------------------
// Kernel 4: per-64-point-block bounding boxes.
// ---------------------------------------------------------------------------
__global__ __launch_bounds__(64) void k_bbox(
    const float4* __restrict__ centS, float4* __restrict__ blo,
    float4* __restrict__ bhi, int F) {
  int b = blockIdx.x;
  int t = threadIdx.x;
  int idx = b * 64 + t;
  bool ok = idx < F;
  float4 v = centS[ok ? idx : 0];
  float lx = ok ? v.x : __builtin_inff(), hx = ok ? v.x : -__builtin_inff();
  float ly = ok ? v.y : __builtin_inff(), hy = ok ? v.y : -__builtin_inff();
  float lz = ok ? v.z : __builtin_inff(), hz = ok ? v.z : -__builtin_inff();
  for (int m = 1; m < 64; m <<= 1) {
    lx = fminf(lx, __shfl_xor(lx, m));
    ly = fminf(ly, __shfl_xor(ly, m));
    lz = fminf(lz, __shfl_xor(lz, m));
    hx = fmaxf(hx, __shfl_xor(hx, m));
    hy = fmaxf(hy, __shfl_xor(hy, m));
    hz = fmaxf(hz, __shfl_xor(hz, m));
  }
  if (t == 0) {
    blo[b] = make_float4(lx, ly, lz, 0.0f);
    bhi[b] = make_float4(hx, hy, hz, 0.0f);
  }
}

// ---------------------------------------------------------------------------
// Kernel 5: tau'[pos] = 20th smallest (incl. self) d2 over a 320-wide Morton
// window, * (1+2e-6) fma-noise margin (valid upper bound: subset order stat
// >= full-set order stat). Also group-max tau; zeroes collect counters.
// ---------------------------------------------------------------------------
__global__ __launch_bounds__(256) void k_tau(
    const float4* __restrict__ centS, float* __restrict__ tauS,
    float* __restrict__ gtau, u32* __restrict__ cntS, int F) {
  __shared__ float s_m[3 * TAU_K * 64];   // 15 KB

  int lane = threadIdx.x & 63;
  int w    = threadIdx.x >> 6;
  int g    = blockIdx.x;
  int myPos = g * 64 + lane;
  bool live = myPos < F;
  float4 me = centS[live ? myPos : 0];

  float L[TAU_K];
  #pragma unroll
  for (int p = 0; p < TAU_K; ++p) L[p] = __builtin_inff();

  int ws0 = g * 64 - 128 + w * (WIN / 4);
  #pragma unroll 2
  for (int t = 0; t < WIN / 4; ++t) {
    int jj = ws0 + t;
    if ((unsigned)jj < (unsigned)F) {     // wave-uniform branch
      float4 cj = centS[jj];
      float dx = me.x - cj.x;
      float dy = me.y - cj.y;
      float dz = me.z - cj.z;
      float d2 = fmaf(dz, dz, fmaf(dy, dy, dx * dx));
      float prev = d2;
      #pragma unroll
      for (int p = 0; p < TAU_K; ++p) {
        float o = L[p];
        L[p] = fminf(o, prev);
        prev = fmaxf(o, d2);
      }
    }
  }

  if (w > 0) {
    #pragma unroll
    for (int p = 0; p < TAU_K; ++p)
      s_m[((w - 1) * TAU_K + p) * 64 + lane] = L[p];
  }
  __syncthreads();

  if (w == 0) {
    for (int wm = 0; wm < 3; ++wm) {
      #pragma unroll
      for (int p = 0; p < TAU_K; ++p) {
        float x = s_m[(wm * TAU_K + p) * 64 + lane];
        float prev = x;
        #pragma unroll
        for (int q = 0; q < TAU_K; ++q) {
          float o = L[q];
          L[q] = fminf(o, prev);
          prev = fmaxf(o, x);
        }
      }
    }
    float t = L[TAU_K - 1] * (1.0f + 2e-6f);
    if (live) { tauS[myPos] = t; cntS[myPos] = 0u; }
    float gm = live ? t : 0.0f;
    #pragma unroll
    for (int m = 1; m < 64; m <<= 1) gm = fmaxf(gm, __shfl_xor(gm, m));
    if (lane == 0) gtau[g] = gm;
  }
}

// ---------------------------------------------------------------------------
// Kernel 6: per-group candidate-block list (bbox prune vs group-max tau).
// ---------------------------------------------------------------------------
__global__ __launch_bounds__(64) void k_blist(
    const float4* __restrict__ blo, const float4* __restrict__ bhi,
    const float* __restrict__ gtau, u32* __restrict__ blist,
    u32* __restrict__ blen, int nblk) {
  int g = blockIdx.x;
  int lane = threadIdx.x;
  float4 gl = blo[g], gh = bhi[g];
  float gt = gtau[g];
  int base = 0;
  for (int b0 = 0; b0 < nblk; b0 += 64) {
    int b = b0 + lane;
    bool keep = false;
    if (b < nblk) {
      float4 lo = blo[b], hi = bhi[b];
      float dx = fmaxf(0.0f, fmaxf(lo.x - gh.x, gl.x - hi.x));
      float dy = fmaxf(0.0f, fmaxf(lo.y - gh.y, gl.y - hi.y));
      float dz = fmaxf(0.0f, fmaxf(lo.z - gh.z, gl.z - hi.z));
      float dmin = ((dx * dx + dy * dy) + dz * dz) * 0.999999f;
      keep = dmin <= gt;
    }
    u64 mask = __ballot(keep);
    int prefix = __popcll(mask & ((1ull << lane) - 1ull));
    if (keep) blist[g * MAXBLK + base + prefix] = (u32)b;
    base += __popcll(mask);
  }
  if (lane == 0) blen[g] = (u32)base;
}

// ---------------------------------------------------------------------------
// Kernel 7: collect all j != pos with exact d2 <= tau'[pos] (superset of the
// true top-19). LDS-buffered appends; count is exact even past cap (keys
// beyond cap dropped -> face flagged for k_fix by count alone).
// ---------------------------------------------------------------------------
__global__ __launch_bounds__(64) void k_collect(
    const float4* __restrict__ centS, const float* __restrict__ tauS,
    const u32* __restrict__ blist, const u32* __restrict__ blen,
    u32* __restrict__ cntS, u64* __restrict__ bufS, int F, int cap) {
  #pragma clang fp contract(off)
  __shared__ u64 lbuf[64 * LCAP];   // 8 KB

  int bid  = blockIdx.x;
  int g    = bid >> 6;          // NSLOT = 64
  int slot = bid & (NSLOT - 1);
  int len  = (int)blen[g];
  if (slot >= len) return;

  int lane = threadIdx.x;
  int myPos = g * 64 + lane;
  bool live = myPos < F;
  float4 me = centS[live ? myPos : 0];
  float tf = live ? tauS[myPos] : -1.0f;
  int n = 0;

  for (int li = slot; li < len; li += NSLOT) {
    int cb = (int)blist[g * MAXBLK + li];
    int base = cb * 64;
    int cnt = (base + 64 <= F) ? 64 : (F - base);
    #pragma unroll 4
    for (int q = 0; q < cnt; ++q) {
      int jj = base + q;                       // wave-uniform
      float4 cj = centS[jj];
      float dx = me.x - cj.x;
      float dy = me.y - cj.y;
      float dz = me.z - cj.z;
      float d2 = (dx * dx + dy * dy) + dz * dz;   // bit-exact reference form
      if (d2 <= tf && jj != myPos) {
        u64 key = (((u64)__float_as_uint(d2)) << 32) | (u64)jj;  // jj: sorted pos
        if (n < LCAP) {
          lbuf[lane * LCAP + n] = key;
          ++n;
        } else {
          u32 pos = atomicAdd(&cntS[myPos], 1u);
          if (pos < (u32)cap) bufS[(size_t)myPos * cap + pos] = key;
        }
      }
    }
    if (n >= 8) {
      u32 basep = atomicAdd(&cntS[myPos], (u32)n);
      for (int i = 0; i < n; ++i) {
        u32 pp = basep + (u32)i;
        if (pp < (u32)cap) bufS[(size_t)myPos * cap + pp] = lbuf[lane * LCAP + i];
      }
      n = 0;
    }
  }
  if (n > 0) {
    u32 basep = atomicAdd(&cntS[myPos], (u32)n);
    for (int i = 0; i < n; ++i) {
      u32 pp = basep + (u32)i;
      if (pp < (u32)cap) bufS[(size_t)myPos * cap + pp] = lbuf[lane * LCAP + i];
    }
  }
}

// ---------------------------------------------------------------------------
// Kernel 8: fast exact top-19 where the collect succeeded (19 <= n <= cap);
// otherwise append face to badlist for k_fix (NO serial rescan here).
// Keys rebuilt with ORIGINAL ids -> lax.top_k's stable tie-break.
// ---------------------------------------------------------------------------
__global__ __launch_bounds__(256) void k_select(
    const u32* __restrict__ ids, const u32* __restrict__ cntS,
    const u64* __restrict__ bufS, int* __restrict__ nearest,
    u32* __restrict__ badlist, u32* __restrict__ badcnt, int F, int cap) {
  int pos = blockIdx.x * 256 + threadIdx.x;
  if (pos >= F) return;

  int n = (int)cntS[pos];
  if (n >= KNN && n <= cap) {
    u64 L[KNN];
    #pragma unroll
    for (int p = 0; p < KNN; ++p) L[p] = INIT_KEY;
    const u64* row = bufS + (size_t)pos * cap;
    for (int i = 0; i < n; ++i) {
      u64 kraw = row[i];
      u32 jpos = (u32)kraw;
      u64 key = (kraw & 0xFFFFFFFF00000000ull) | (u64)ids[jpos];
      if (key < L[KNN - 1]) {
        u64 prev = key;
        #pragma unroll
        for (int p = 0; p < KNN; ++p) {
          u64 o = L[p];
          L[p] = prev < o ? prev : o;
          prev = key < o ? o : key;
        }
      }
    }
    u32 myId = ids[pos];
    #pragma unroll
    for (int p = 0; p < KNN; ++p)
      nearest[(size_t)myId * KNN + p] = (int)(u32)L[p];
  } else {
    badlist[atomicAdd(badcnt, 1u)] = (u32)pos;
  }
}

// ---------------------------------------------------------------------------
// Kernel 9: exact wave-parallel kNN for bad faces. One 64-lane wave per bad
// face (strided over badlist): per-lane stride-64 top-20 register lists
// (coalesced loads), then 19 rounds of wave-wide u64-min extraction.
// Cost ~2-3 us per face, fully parallel; removes the straggler tail.
// ---------------------------------------------------------------------------
__global__ __launch_bounds__(64) void k_fix(
    const float4* __restrict__ centS, const u32* __restrict__ ids,
    const u32* __restrict__ badlist, const u32* __restrict__ badcnt,
    int* __restrict__ nearest, int F) {
  #pragma clang fp contract(off)
  int nbad = (int)*badcnt;
  int lane = threadIdx.x;

  for (int bi = blockIdx.x; bi < nbad; bi += FIXBLKS) {
    int pos = (int)badlist[bi];
    float4 me = centS[pos];

    u64 L[TAU_K];
    #pragma unroll
    for (int p = 0; p < TAU_K; ++p) L[p] = INIT_KEY;

    for (int jj = lane; jj < F; jj += 64) {
      float4 cj = centS[jj];
      float dx = me.x - cj.x;
      float dy = me.y - cj.y;
      float dz = me.z - cj.z;
      float d2 = (dx * dx + dy * dy) + dz * dz;    // bit-exact reference form
      u64 key = (((u64)__float_as_uint(d2)) << 32) | (u64)ids[jj];
      key = (jj == pos) ? INIT_KEY : key;          // exclude self
      if (key < L[TAU_K - 1]) {
        u64 prev = key;
        #pragma unroll
        for (int p = 0; p < TAU_K; ++p) {
          u64 o = L[p];
          L[p] = prev < o ? prev : o;
          prev = key < o ? o : key;
        }
      }
    }

    // 19 rounds of wave-min extraction (keys unique -> single winner).
    u32 myId = ids[pos];
    int h = 0;
    for (int r = 0; r < KNN; ++r) {
      u64 myv = (h < TAU_K) ? L[h] : INIT_KEY;
      u64 m = myv;
      #pragma unroll
      for (int s = 1; s < 64; s <<= 1) {
        u64 o = __shfl_xor(m, s);
        m = o < m ? o : m;
      }
      if (myv == m && m != INIT_KEY) ++h;
      if (lane == 0) nearest[(size_t)myId * KNN + r] = (int)(u32)m;
    }
  }
}

// ---------------------------------------------------------------------------
// Kernel 10: one thread per (face, neighbor): 3x3 segment-pair crossings.
// ---------------------------------------------------------------------------
__global__ __launch_bounds__(256) void k_cross(
    const float4* __restrict__ edges, const int* __restrict__ nearest,
    int* __restrict__ ccbuf, int total) {
  #pragma clang fp contract(off)
  int idx = blockIdx.x * 256 + threadIdx.x;
  if (idx >= total) return;
  int f = idx / KNN;
  int g = nearest[idx];

  float e[3][3], nb[3][3];
  #pragma unroll
  for (int a = 0; a < 3; ++a) {
    float4 t = edges[f * 3 + a];
    e[a][0] = t.x; e[a][1] = t.y; e[a][2] = t.z;
  }
  #pragma unroll
  for (int b = 0; b < 3; ++b) {
    float4 t = edges[g * 3 + b];
    nb[b][0] = t.x; nb[b][1] = t.y; nb[b][2] = t.z;
  }

  int cc = 0;
  #pragma unroll
  for (int a = 0; a < 3; ++a) {
    #pragma unroll
    for (int b = 0; b < 3; ++b) {
      float c0 = e[a][1] * nb[b][2] - e[a][2] * nb[b][1];
      float c1 = e[a][2] * nb[b][0] - e[a][0] * nb[b][2];
      float c2 = e[a][0] * nb[b][1] - e[a][1] * nb[b][0];
      float den = (c0 * e[a][0] + c1 * e[a][1]) + c2 * e[a][2];
      float tn  = (c0 * nb[b][0] + c1 * nb[b][1]) + c2 * nb[b][2];
      float un  = (c0 * e[b][0]  + c1 * e[b][1])  + c2 * e[b][2];
      float t = tn / den;
      float u = un / den;
      if (t >= 0.0f && t <= 1.0f && u >= 0.0f && u <= 1.0f) ++cc;
    }
  }
  ccbuf[idx] = cc;
}

// ---------------------------------------------------------------------------
// Kernel 11: per-face weighted sum, block-reduced.
// ---------------------------------------------------------------------------
__global__ __launch_bounds__(256) void k_wsum(
    const int* __restrict__ ccbuf, const float* __restrict__ probs,
    float* __restrict__ partial, int F) {
  int f = blockIdx.x * 256 + threadIdx.x;
  float w = 0.0f;
  if (f < F) {
    int c = 0;
    #pragma unroll
    for (int s = 0; s < KNN; ++s) c += ccbuf[(size_t)f * KNN + s];
    w = probs[f] * (float)c;
  }
  __shared__ float red[256];
  red[threadIdx.x] = w;
  __syncthreads();
  #pragma unroll
  for (int s = 128; s > 0; s >>= 1) {
    if (threadIdx.x < s) red[threadIdx.x] += red[threadIdx.x + s];
    __syncthreads();
  }
  if (threadIdx.x == 0) partial[blockIdx.x] = red[0];
}

// ---------------------------------------------------------------------------
// Kernel 12: deterministic final reduction; /F exact (F = 2^14)
// ---------------------------------------------------------------------------
__global__ void k_final(const float* __restrict__ partial, float* __restrict__ out,
                        int nblk, float invF) {
  if (threadIdx.x == 0 && blockIdx.x == 0) {
    float s = 0.0f;
    for (int i = 0; i < nblk; ++i) s += partial[i];
    out[0] = s * invF;
  }
}

extern "C" void kernel_launch(void* const* d_in, const int* in_sizes, int n_in,
                              void* d_out, int out_size, void* d_ws, size_t ws_size,
                              hipStream_t stream) {
  const float* verts = (const float*)d_in[0];
  const int*   faces = (const int*)d_in[1];
  const float* probs = (const float*)d_in[2];
  float* out = (float*)d_out;
  const int F = in_sizes[2];            // 16384
  const int total = F * KNN;
  const int nblk64 = (F + 63) / 64;     // 256 groups / candidate blocks

  char* ws = (char*)d_ws;
  size_t off = 0;
  auto take = [&](size_t bytes) { char* p = ws + off; off += (bytes + 255) & ~(size_t)255; return p; };

  float4* cent    = (float4*)take((size_t)F * sizeof(float4));
  float4* edges   = (float4*)take((size_t)F * 3 * sizeof(float4));
  u32*    cellkey = (u32*)   take((size_t)F * sizeof(u32));
  u32*    hist    = (u32*)   take((size_t)NCELLS * sizeof(u32));
  u32*    cursor  = (u32*)   take((size_t)NCELLS * sizeof(u32));
  u32*    ids     = (u32*)   take((size_t)F * sizeof(u32));
  float4* centS   = (float4*)take((size_t)F * sizeof(float4));
  float4* blo     = (float4*)take((size_t)nblk64 * sizeof(float4));
  float4* bhi     = (float4*)take((size_t)nblk64 * sizeof(float4));
  float*  tauS    = (float*) take((size_t)F * sizeof(float));
  float*  gtau    = (float*) take((size_t)nblk64 * sizeof(float));
  u32*    cntS    = (u32*)   take((size_t)F * sizeof(u32));
  u32*    blist   = (u32*)   take((size_t)nblk64 * MAXBLK * sizeof(u32));
  u32*    blen    = (u32*)   take((size_t)nblk64 * sizeof(u32));
  int*    nearest = (int*)   take((size_t)total * sizeof(int));
  u32*    badlist = (u32*)   take((size_t)F * sizeof(u32));
  u32*    badcnt  = (u32*)   take(256);
  float*  partial = (float*) take(256 * sizeof(float));

  // bufS (k_collect -> k_select) and ccbuf (k_cross -> k_wsum) share the
  // tail region: disjoint lifetimes.
  size_t avail = (ws_size > off) ? (ws_size - off) : 0;
  size_t capz = avail / ((size_t)F * sizeof(u64));
  int cap = capz > 64 ? 64 : (int)capz;      // per-face collect capacity
  u64* bufS  = (u64*)(ws + off);
  int* ccbuf = (int*)(ws + off);

  int nblk256 = (F + 255) / 256;        // 64

  hipMemsetAsync(hist, 0, (size_t)NCELLS * sizeof(u32), stream);
  hipMemsetAsync(badcnt, 0, sizeof(u32), stream);
  k_prep   <<<nblk256, 256, 0, stream>>>(verts, faces, cent, edges, cellkey, hist, F);
  k_scan   <<<1, 1024, 0, stream>>>(hist, cursor);
  k_scatter<<<nblk256, 256, 0, stream>>>(cent, cellkey, cursor, ids, centS, F);
  k_bbox   <<<nblk64, 64, 0, stream>>>(centS, blo, bhi, F);
  k_tau    <<<nblk64, 256, 0, stream>>>(centS, tauS, gtau, cntS, F);
  k_blist  <<<nblk64, 64, 0, stream>>>(blo, bhi, gtau, blist, blen, nblk64);
  k_collect<<<nblk64 * NSLOT, 64, 0, stream>>>(centS, tauS, blist, blen, cntS, bufS, F, cap);
  k_select <<<nblk256, 256, 0, stream>>>(ids, cntS, bufS, nearest, badlist, badcnt, F, cap);
  k_fix    <<<FIXBLKS, 64, 0, stream>>>(centS, ids, badlist, badcnt, nearest, F);
  k_cross  <<<(total + 255) / 256, 256, 0, stream>>>(edges, nearest, ccbuf, total);
  k_wsum   <<<nblk256, 256, 0, stream>>>(ccbuf, probs, partial, F);
  k_final  <<<1, 64, 0, stream>>>(partial, out, nblk256, 1.0f / (float)F);
}